// Round 9
// baseline (427.487 us; speedup 1.0000x reference)
//
#include <hip/hip_runtime.h>
#include <hip/hip_bf16.h>

typedef __bf16 bf16;
typedef __attribute__((ext_vector_type(2))) __bf16 bf16x2;
typedef __attribute__((ext_vector_type(4))) __bf16 bf16x4;
typedef __attribute__((ext_vector_type(8))) __bf16 bf16x8;
typedef __attribute__((ext_vector_type(4))) float f32x4;

#define NB 2
#define SEQ 1024
#define HIDN 4096
#define NH 32
#define NKV 8
#define DH 128
#define QKV_N 6144
static constexpr float SCALE = 0.08838834764831845f;  // 1/sqrt(128)

#define MFMA(a, b, c) __builtin_amdgcn_mfma_f32_16x16x32_bf16((a), (b), (c), 0, 0, 0)

__device__ __forceinline__ void async16(const void* g, void* l) {
  __builtin_amdgcn_global_load_lds(
      (const __attribute__((address_space(1))) unsigned int*)g,
      (__attribute__((address_space(3))) unsigned int*)l,
      16, 0, 0);
}

__device__ __forceinline__ void barrier_raw() {
  asm volatile("" ::: "memory");
  __builtin_amdgcn_s_barrier();
  asm volatile("" ::: "memory");
}
#define VMCNT(n) asm volatile("s_waitcnt vmcnt(" #n ")" ::: "memory")

// ---------------- f32 -> bf16 convert (vector) ----------------
__global__ __launch_bounds__(256) void cvt_f32_bf16(const float* __restrict__ src,
                                                    bf16* __restrict__ dst, int n4) {
  int i = blockIdx.x * 256 + threadIdx.x;
  if (i >= n4) return;
  const float4 v = ((const float4*)src)[i];
  bf16x4 o = {(bf16)v.x, (bf16)v.y, (bf16)v.z, (bf16)v.w};
  ((bf16x4*)dst)[i] = o;
}

// ---------------- transpose + convert: dst[N][K] = (bf16)src[K][N] ----------------
__global__ __launch_bounds__(256) void transpose_cvt(const float* __restrict__ src,
                                                     bf16* __restrict__ dst, int R, int C) {
  __shared__ float tl[32][33];
  const int j0 = blockIdx.x * 32, i0 = blockIdx.y * 32;
  const int tr = threadIdx.x >> 5, tc = threadIdx.x & 31;
#pragma unroll
  for (int p = 0; p < 4; ++p)
    tl[tr + p * 8][tc] = src[(size_t)(i0 + tr + p * 8) * C + j0 + tc];
  __syncthreads();
#pragma unroll
  for (int p = 0; p < 4; ++p)
    dst[(size_t)(j0 + tr + p * 8) * R + i0 + tc] = (bf16)tl[tc][tr + p * 8];
}

// ======== A-global / B-LDS bf16 GEMM, BM=128, BK=32, 4 rotating B buffers ========
// C[M][N] = A[M][K] * BT[N][K]^T.  512 thr = 8 waves (2M x 4N); per-wave 64 x BN/4.
// gemm1 was LDS-BW-bound (R8: 112 KB LDS/tile ~ 875cy vs 230cy MFMA).  Fix: A-frags
// load global->VGPR (double-buffered, L1 serves the 4x wn re-read); LDS carries B only
// (24K stage + 48K read = 72KB/tile).  1 barrier/tile.  vmcnt ledger (in-order
// decrement => undercount safe): steady VMCNT(2*LB+8) certifies sB(kt+1) at tile kt;
// compiler inserts precise waits for the A-register loads.  Swizzle: 64B rows,
// slot16 ^= (row>>1)&3, pre-swizzled global source (0 conflicts, verified R3-R8).
template <int BN, int OUT_BF16>
__global__ __launch_bounds__(512, 2) void gemm_ag(const bf16* __restrict__ A,
                                                  const bf16* __restrict__ BT,
                                                  void* __restrict__ Cout,
                                                  int N, int K) {
  extern __shared__ char smem[];
  constexpr int CB = BN * 32 * 2;   // 24 / 16 KiB per K-tile B buffer
  constexpr int LB = CB / 8192;     // stage instr / thread / K-tile (3 or 2)
  constexpr int FN = BN / 64;       // B frags per wave (6 or 4)
  const int t = threadIdx.x, lane = t & 63, w = t >> 6;
  const int l16 = lane & 15, lq = lane >> 4;
  const int wm = w >> 2, wn = w & 3;

  const int nwg = gridDim.x;  // 256
  const int lin = ((int)blockIdx.x & 7) * (nwg >> 3) + ((int)blockIdx.x >> 3);
  const int m0 = (lin & 15) * 128;  // m-inner: XCD chunk keeps its B panels L2-hot
  const int n0 = (lin >> 4) * BN;

  // B staging sources (pre-swizzled global, linear LDS dest)
  const int srow = t >> 2;
  const int sslot = (t & 3) ^ ((srow >> 1) & 3);  // +128 rows -> same xor
  const bf16* gB[LB];
#pragma unroll
  for (int u = 0; u < LB; ++u)
    gB[u] = BT + (size_t)(n0 + u * 128 + srow) * K + sslot * 8;

  // A fragment pointers (per-lane global, 16 rows x 16B per frag; L1-served re-reads)
  const bf16* aptr[4];
#pragma unroll
  for (int f = 0; f < 4; ++f)
    aptr[f] = A + (size_t)(m0 + wm * 64 + f * 16 + l16) * K + lq * 8;

  // swizzled B fragment byte offsets
  int bbyte[FN];
#pragma unroll
  for (int j = 0; j < FN; ++j) {
    const int r = wn * (BN / 4) + j * 16 + l16;
    bbyte[j] = r * 64 + ((lq ^ ((r >> 1) & 3)) << 4);
  }

  auto stageB = [&](int kt) {
    char* d = smem + (kt & 3) * CB + t * 16;
#pragma unroll
    for (int u = 0; u < LB; ++u) async16(gB[u] + (size_t)kt * 32, d + u * 8192);
  };

  f32x4 acc[4][FN] = {};
  const int NT = K >> 5;  // 128

  bf16x8 aCur[4], aNxt[4];

  // prologue: B tiles 0..2 staged; A tile 0 in regs; certify sB(0)
  stageB(0);
#pragma unroll
  for (int f = 0; f < 4; ++f) aCur[f] = *(const bf16x8*)(aptr[f]);
  stageB(1);
  stageB(2);
  if constexpr (LB == 3) { VMCNT(10); } else { VMCNT(8); }  // younger: A0(~4)+sB1+sB2
  barrier_raw();

  auto tile = [&](int kt, bf16x8(&aC)[4], bf16x8(&aN)[4]) {
    const char* buf = smem + (kt & 3) * CB;
    if (kt + 1 < NT) {
#pragma unroll
      for (int f = 0; f < 4; ++f)
        aN[f] = *(const bf16x8*)(aptr[f] + (size_t)(kt + 1) * 32);
    }
    if (kt + 3 < NT) stageB(kt + 3);
    bf16x8 bfr[FN];
#pragma unroll
    for (int j = 0; j < FN; ++j) bfr[j] = *(const bf16x8*)(buf + bbyte[j]);
    if (kt + 3 < NT) {
      if constexpr (LB == 3) { VMCNT(14); } else { VMCNT(12); }  // 2*(LB+4): sB(kt+1) ok
    } else {
      VMCNT(0);
    }
    barrier_raw();
    __builtin_amdgcn_s_setprio(1);
#pragma unroll
    for (int f = 0; f < 4; ++f)
#pragma unroll
      for (int j = 0; j < FN; ++j) acc[f][j] = MFMA(aC[f], bfr[j], acc[f][j]);
    __builtin_amdgcn_s_setprio(0);
  };

  for (int kt = 0; kt < NT; kt += 2) {
    tile(kt, aCur, aNxt);
    tile(kt + 1, aNxt, aCur);
  }

#pragma unroll
  for (int f = 0; f < 4; ++f)
#pragma unroll
    for (int j = 0; j < FN; ++j)
#pragma unroll
      for (int r = 0; r < 4; ++r) {
        const int row = m0 + wm * 64 + f * 16 + lq * 4 + r;
        const int col = n0 + wn * (BN / 4) + j * 16 + l16;
        if (OUT_BF16)
          ((bf16*)Cout)[(size_t)row * N + col] = (bf16)acc[f][j][r];
        else
          ((float*)Cout)[(size_t)row * N + col] = acc[f][j][r];
      }
}

// ---------------- RoPE + reshape ----------------
__global__ __launch_bounds__(256) void rope_reshape(const bf16* __restrict__ qkv,
                                                    const float* __restrict__ cosp,
                                                    const float* __restrict__ sinp,
                                                    bf16* __restrict__ Qo,
                                                    bf16* __restrict__ Ko,
                                                    bf16* __restrict__ VTo) {
  const int row = blockIdx.x;          // b*SEQ + s
  const int b = row >> 10, s = row & 1023;
  const bf16* src = qkv + (size_t)row * QKV_N;
  for (int p = threadIdx.x; p < QKV_N / 2; p += 256) {
    const int col = p * 2;
    bf16x2 x = *(const bf16x2*)&src[col];
    const float x1 = (float)x.x, x2 = (float)x.y;
    if (col < 4096) {
      const int h = col >> 7, d = col & 127, i = (col & 127) >> 1;
      const float c = cosp[s * 64 + i], sn = sinp[s * 64 + i];
      bf16x2 o = {(bf16)((x1 * c - x2 * sn) * SCALE), (bf16)((x1 * sn + x2 * c) * SCALE)};
      *(bf16x2*)&Qo[((size_t)(b * NH + h) * SEQ + s) * DH + d] = o;
    } else if (col < 5120) {
      const int idx = col - 4096;
      const int kvh = idx >> 7, d = idx & 127, i = (idx & 127) >> 1;
      const float c = cosp[s * 64 + i], sn = sinp[s * 64 + i];
      bf16x2 o = {(bf16)(x1 * c - x2 * sn), (bf16)(x1 * sn + x2 * c)};
      *(bf16x2*)&Ko[((size_t)(b * NKV + kvh) * SEQ + s) * DH + d] = o;
    } else {
      const int idx = col - 5120;
      const int kvh = idx >> 7, d = idx & 127;
      bf16* vbase = VTo + ((size_t)(b * NKV + kvh) * DH + d) * SEQ + s;
      vbase[0] = x.x;
      vbase[SEQ] = x.y;
    }
  }
}

// ======== causal GQA flash attention v2: 8-wave blocks, LDS-staged K/V (R8, kept) ====
__global__ __launch_bounds__(512, 2) void flash_attn(const bf16* __restrict__ Q,
                                                     const bf16* __restrict__ K,
                                                     const bf16* __restrict__ VT,
                                                     bf16* __restrict__ O) {
  extern __shared__ char smem[];
  const int t = threadIdx.x, lane = t & 63, w = t >> 6;
  const int l16 = lane & 15, lq = lane >> 4;
  const int p = blockIdx.x;
  const int b = p >> 7, h = (p >> 2) & 31, Tb = p & 3;
  const int kvh = h >> 2;

  const bf16* Qb = Q + (size_t)(b * NH + h) * SEQ * DH;
  const bf16* Kb = K + (size_t)(b * NKV + kvh) * SEQ * DH;
  const bf16* Vb = VT + (size_t)(b * NKV + kvh) * DH * SEQ;

  const int qrA = Tb * 128 + w * 16;
  const int qrB = (7 - Tb) * 128 + w * 16;
  const int nAw = (qrA >> 6) + 1;
  const int nBw = (qrB >> 6) + 1;
  const int NT = 16 - 2 * Tb;

  bf16* plw = (bf16*)(smem + 98304) + w * (2 * 16 * 72);

  const bf16* kSrc = Kb + (size_t)(t >> 4) * DH + 8 * ((t & 15) ^ ((t >> 4) & 7));
  const bf16* vSrc = Vb + (size_t)(t >> 3) * SEQ + 8 * ((t & 7) ^ ((t >> 3) & 7));

  auto stage = [&](int kv) {
    char* bufb = smem + (kv % 3) * 32768;
    async16(kSrc + (size_t)(kv * 64) * DH, bufb + t * 16);
    async16(kSrc + (size_t)(kv * 64 + 32) * DH, bufb + 8192 + t * 16);
    async16(vSrc + kv * 64, bufb + 16384 + t * 16);
    async16(vSrc + (size_t)64 * SEQ + kv * 64, bufb + 24576 + t * 16);
  };

  int KX[4], VX[2];
#pragma unroll
  for (int kk = 0; kk < 4; ++kk) KX[kk] = ((kk * 4 + lq) ^ (l16 & 7)) << 4;
#pragma unroll
  for (int c = 0; c < 2; ++c) VX[c] = ((c * 4 + lq) ^ (l16 & 7)) << 4;

  bf16x8 qfA[4], qfB[4];
#pragma unroll
  for (int kk = 0; kk < 4; ++kk) {
    qfA[kk] = *(const bf16x8*)&Qb[(size_t)(qrA + l16) * DH + kk * 32 + lq * 8];
    qfB[kk] = *(const bf16x8*)&Qb[(size_t)(qrB + l16) * DH + kk * 32 + lq * 8];
  }

  f32x4 accA[8] = {}, accB[8] = {};
  float mA[4], lA[4], mB[4], lB[4];
#pragma unroll
  for (int r = 0; r < 4; ++r) {
    mA[r] = mB[r] = -INFINITY;
    lA[r] = lB[r] = 0.f;
  }

  auto finish = [&](f32x4(&s)[4], float(&m)[4], float(&l)[4], f32x4(&acc)[8], int slot,
                    bool mask, int kv, int qr) {
    if (mask) {
#pragma unroll
      for (int nt = 0; nt < 4; ++nt)
#pragma unroll
        for (int r = 0; r < 4; ++r)
          if (kv * 64 + nt * 16 + l16 > qr + lq * 4 + r) s[nt][r] = -INFINITY;
    }
#pragma unroll
    for (int r = 0; r < 4; ++r) {
      float mx = fmaxf(fmaxf(s[0][r], s[1][r]), fmaxf(s[2][r], s[3][r]));
#pragma unroll
      for (int off = 1; off < 16; off <<= 1) mx = fmaxf(mx, __shfl_xor(mx, off));
      const float mn = fmaxf(m[r], mx);
      const float corr = __expf(m[r] - mn);
      m[r] = mn;
      float ps = 0.f;
#pragma unroll
      for (int nt = 0; nt < 4; ++nt) {
        const float pv = __expf(s[nt][r] - mn);
        s[nt][r] = pv;
        ps += pv;
      }
#pragma unroll
      for (int off = 1; off < 16; off <<= 1) ps += __shfl_xor(ps, off);
      l[r] = l[r] * corr + ps;
#pragma unroll
      for (int j = 0; j < 8; ++j) acc[j][r] *= corr;
    }
#pragma unroll
    for (int nt = 0; nt < 4; ++nt)
#pragma unroll
      for (int r = 0; r < 4; ++r)
        plw[slot * 1152 + (lq * 4 + r) * 72 + nt * 16 + l16] = (bf16)s[nt][r];
  };

  stage(0);
  stage(1);
  VMCNT(4);
  barrier_raw();

  for (int kv = 0; kv < NT; ++kv) {
    const char* kbuf = smem + (kv % 3) * 32768;
    const char* vbuf = kbuf + 16384;
    if (kv + 2 < NT) stage(kv + 2);

    if (kv < nAw) {
      f32x4 sA[4] = {}, sB[4] = {};
      __builtin_amdgcn_s_setprio(1);
#pragma unroll
      for (int nt = 0; nt < 4; ++nt) {
        const char* kr = kbuf + (nt * 16 + l16) * 256;
        bf16x8 k0 = *(const bf16x8*)(kr + KX[0]);
        bf16x8 k1 = *(const bf16x8*)(kr + KX[1]);
        bf16x8 k2 = *(const bf16x8*)(kr + KX[2]);
        bf16x8 k3 = *(const bf16x8*)(kr + KX[3]);
        sA[nt] = MFMA(qfA[0], k0, sA[nt]);
        sB[nt] = MFMA(qfB[0], k0, sB[nt]);
        sA[nt] = MFMA(qfA[1], k1, sA[nt]);
        sB[nt] = MFMA(qfB[1], k1, sB[nt]);
        sA[nt] = MFMA(qfA[2], k2, sA[nt]);
        sB[nt] = MFMA(qfB[2], k2, sB[nt]);
        sA[nt] = MFMA(qfA[3], k3, sA[nt]);
        sB[nt] = MFMA(qfB[3], k3, sB[nt]);
      }
      __builtin_amdgcn_s_setprio(0);
      finish(sA, mA, lA, accA, 0, kv == nAw - 1, kv, qrA);
      finish(sB, mB, lB, accB, 1, kv == nBw - 1, kv, qrB);
      bf16x8 pA0 = *(const bf16x8*)&plw[l16 * 72 + lq * 8];
      bf16x8 pA1 = *(const bf16x8*)&plw[l16 * 72 + 32 + lq * 8];
      bf16x8 pB0 = *(const bf16x8*)&plw[1152 + l16 * 72 + lq * 8];
      bf16x8 pB1 = *(const bf16x8*)&plw[1152 + l16 * 72 + 32 + lq * 8];
      __builtin_amdgcn_s_setprio(1);
#pragma unroll
      for (int j = 0; j < 8; ++j) {
        const char* vr = vbuf + (j * 16 + l16) * 128;
        bf16x8 v0 = *(const bf16x8*)(vr + VX[0]);
        bf16x8 v1 = *(const bf16x8*)(vr + VX[1]);
        accA[j] = MFMA(pA0, v0, accA[j]);
        accB[j] = MFMA(pB0, v0, accB[j]);
        accA[j] = MFMA(pA1, v1, accA[j]);
        accB[j] = MFMA(pB1, v1, accB[j]);
      }
      __builtin_amdgcn_s_setprio(0);
    } else if (kv < nBw) {
      f32x4 sB[4] = {};
      __builtin_amdgcn_s_setprio(1);
#pragma unroll
      for (int nt = 0; nt < 4; ++nt) {
        const char* kr = kbuf + (nt * 16 + l16) * 256;
        bf16x8 k0 = *(const bf16x8*)(kr + KX[0]);
        bf16x8 k1 = *(const bf16x8*)(kr + KX[1]);
        bf16x8 k2 = *(const bf16x8*)(kr + KX[2]);
        bf16x8 k3 = *(const bf16x8*)(kr + KX[3]);
        sB[nt] = MFMA(qfB[0], k0, sB[nt]);
        sB[nt] = MFMA(qfB[1], k1, sB[nt]);
        sB[nt] = MFMA(qfB[2], k2, sB[nt]);
        sB[nt] = MFMA(qfB[3], k3, sB[nt]);
      }
      __builtin_amdgcn_s_setprio(0);
      finish(sB, mB, lB, accB, 1, kv == nBw - 1, kv, qrB);
      bf16x8 pB0 = *(const bf16x8*)&plw[1152 + l16 * 72 + lq * 8];
      bf16x8 pB1 = *(const bf16x8*)&plw[1152 + l16 * 72 + 32 + lq * 8];
      __builtin_amdgcn_s_setprio(1);
#pragma unroll
      for (int j = 0; j < 8; ++j) {
        const char* vr = vbuf + (j * 16 + l16) * 128;
        bf16x8 v0 = *(const bf16x8*)(vr + VX[0]);
        bf16x8 v1 = *(const bf16x8*)(vr + VX[1]);
        accB[j] = MFMA(pB0, v0, accB[j]);
        accB[j] = MFMA(pB1, v1, accB[j]);
      }
      __builtin_amdgcn_s_setprio(0);
    }

    if (kv + 2 < NT) { VMCNT(4); } else { VMCNT(0); }
    barrier_raw();
  }

  auto wout = [&](f32x4(&acc)[8], float(&l)[4], int qr) {
#pragma unroll
    for (int r = 0; r < 4; ++r) {
      const float inv = 1.f / l[r];
      const size_t orow = ((size_t)b * SEQ + qr + lq * 4 + r) * HIDN + h * DH;
#pragma unroll
      for (int j = 0; j < 8; ++j) O[orow + j * 16 + l16] = (bf16)(acc[j][r] * inv);
    }
  };
  wout(accA, lA, qrA);
  wout(accB, lB, qrB);
}

extern "C" void kernel_launch(void* const* d_in, const int* in_sizes, int n_in,
                              void* d_out, int out_size, void* d_ws, size_t ws_size,
                              hipStream_t stream) {
  const float* hidden = (const float*)d_in[0];
  const float* cosp = (const float*)d_in[1];
  const float* sinp = (const float*)d_in[2];
  const float* wqkv = (const float*)d_in[3];
  const float* wo = (const float*)d_in[4];
  float* out = (float*)d_out;

  char* ws = (char*)d_ws;
  bf16* hiddenB = (bf16*)(ws);                 // 16,777,216   [2048][4096]
  bf16* wqkvT  = (bf16*)(ws + 16777216);       // 50,331,648   [6144][4096]
  bf16* woT    = (bf16*)(ws + 67108864);       // 33,554,432   [4096][4096]
  bf16* qkvB   = (bf16*)(ws + 100663296);      // 25,165,824   [2048][6144]
  bf16* Qb     = (bf16*)(ws + 125829120);      // 16,777,216   [2][32][1024][128]
  bf16* Kb     = (bf16*)(ws + 142606336);      //  4,194,304   [2][8][1024][128]
  bf16* VTb    = (bf16*)(ws + 146800640);      //  4,194,304   [2][8][128][1024]
  bf16* attnB  = hiddenB;                      // alias: hiddenB dead after gemm1

  cvt_f32_bf16<<<8192, 256, 0, stream>>>(hidden, hiddenB, 2097152);
  transpose_cvt<<<dim3(192, 128), 256, 0, stream>>>(wqkv, wqkvT, 4096, 6144);
  transpose_cvt<<<dim3(128, 128), 256, 0, stream>>>(wo, woT, 4096, 4096);
  gemm_ag<384, 1><<<dim3(256), 512, 98304, stream>>>(hiddenB, wqkvT, qkvB, 6144, 4096);
  rope_reshape<<<2048, 256, 0, stream>>>(qkvB, cosp, sinp, Qb, Kb, VTb);
  flash_attn<<<dim3(256), 512, 135168, stream>>>(Qb, Kb, VTb, attnB);
  gemm_ag<256, 0><<<dim3(256), 512, 65536, stream>>>(attnB, woT, out, 4096, 4096);
}

// Round 10
// 300.301 us; speedup vs baseline: 1.4235x; 1.4235x over previous
//
#include <hip/hip_runtime.h>
#include <hip/hip_bf16.h>

typedef __bf16 bf16;
typedef __attribute__((ext_vector_type(2))) __bf16 bf16x2;
typedef __attribute__((ext_vector_type(4))) __bf16 bf16x4;
typedef __attribute__((ext_vector_type(8))) __bf16 bf16x8;
typedef __attribute__((ext_vector_type(4))) float f32x4;

#define NB 2
#define SEQ 1024
#define HIDN 4096
#define NH 32
#define NKV 8
#define DH 128
#define QKV_N 6144
static constexpr float SCALE = 0.08838834764831845f;  // 1/sqrt(128)

#define MFMA(a, b, c) __builtin_amdgcn_mfma_f32_16x16x32_bf16((a), (b), (c), 0, 0, 0)

__device__ __forceinline__ void async16(const void* g, void* l) {
  __builtin_amdgcn_global_load_lds(
      (const __attribute__((address_space(1))) unsigned int*)g,
      (__attribute__((address_space(3))) unsigned int*)l,
      16, 0, 0);
}

__device__ __forceinline__ void barrier_raw() {
  asm volatile("" ::: "memory");
  __builtin_amdgcn_s_barrier();
  asm volatile("" ::: "memory");
}
#define VMCNT(n) asm volatile("s_waitcnt vmcnt(" #n ")" ::: "memory")
#define LGKM0 asm volatile("s_waitcnt lgkmcnt(0)" ::: "memory")

// ---------------- f32 -> bf16 convert (vector) ----------------
__global__ __launch_bounds__(256) void cvt_f32_bf16(const float* __restrict__ src,
                                                    bf16* __restrict__ dst, int n4) {
  int i = blockIdx.x * 256 + threadIdx.x;
  if (i >= n4) return;
  const float4 v = ((const float4*)src)[i];
  bf16x4 o = {(bf16)v.x, (bf16)v.y, (bf16)v.z, (bf16)v.w};
  ((bf16x4*)dst)[i] = o;
}

// ---------------- transpose + convert: dst[N][K] = (bf16)src[K][N] ----------------
__global__ __launch_bounds__(256) void transpose_cvt(const float* __restrict__ src,
                                                     bf16* __restrict__ dst, int R, int C) {
  __shared__ float tl[32][33];
  const int j0 = blockIdx.x * 32, i0 = blockIdx.y * 32;
  const int tr = threadIdx.x >> 5, tc = threadIdx.x & 31;
#pragma unroll
  for (int p = 0; p < 4; ++p)
    tl[tr + p * 8][tc] = src[(size_t)(i0 + tr + p * 8) * C + j0 + tc];
  __syncthreads();
#pragma unroll
  for (int p = 0; p < 4; ++p)
    dst[(size_t)(j0 + tr + p * 8) * R + i0 + tc] = (bf16)tl[tc][tr + p * 8];
}

// ======== Deep-pipelined bf16 GEMM with reg-fragment software pipeline ========
// BM=128, BK=32, 512 thr (8 waves 2Mx4N), 4 rotating LDS K-tile buffers (R7/R8 base).
// NEW (R10): ldfrag(kt+1) issued BEFORE MFMA(kt) -> LDS-read pipe overlaps MFMA pipe
// (R8 ran them serialized: 1879 cy/tile vs pipe maxima ~940 each).
// Ledger per tile kt: stage(kt+3); VMCNT(2L) certifies kt+1 (outstanding {kt+1..kt+3}
// -> wait-to-2L retires kt+1); LGKM0 (free; completes ldfrag(kt), makes stage(kt+4)'s
// WAR on buf kt&3 safe across the barrier); barrier; ldfrag(kt+1); MFMA(kt).
// Swizzle: 64B rows, slot16 ^= (row>>1)&3, pre-swizzled global source (0 conflicts).
template <int BN, int OUT_BF16>
__global__ __launch_bounds__(512, 2) void gemm_dp2(const bf16* __restrict__ A,
                                                   const bf16* __restrict__ BT,
                                                   void* __restrict__ Cout,
                                                   int N, int K) {
  extern __shared__ char smem[];
  constexpr int CA = 128 * 32 * 2;       // 8 KiB A chunk
  constexpr int CB = BN * 32 * 2;        // 24 / 16 KiB B chunk
  constexpr int BUF = CA + CB;           // one K-tile buffer
  constexpr int LTOT = 1 + BN / 128;     // stage instr / thread / K-tile (4 or 3)
  constexpr int FN = BN / 64;            // B frags per wave (6 or 4)
  const int t = threadIdx.x, lane = t & 63, w = t >> 6;
  const int l16 = lane & 15, lq = lane >> 4;
  const int wm = w >> 2, wn = w & 3;

  const int nwg = gridDim.x;  // 256
  const int lin = ((int)blockIdx.x & 7) * (nwg >> 3) + ((int)blockIdx.x >> 3);
  const int m0 = (lin & 15) * 128;  // m-inner: XCD chunk keeps its B panels L2-hot
  const int n0 = (lin >> 4) * BN;

  const int sslot = (t & 3) ^ ((t >> 3) & 3);
  const bf16* gsrc[LTOT];
  gsrc[0] = A + (size_t)(m0 + (t >> 2)) * K + sslot * 8;
#pragma unroll
  for (int u = 1; u < LTOT; ++u)
    gsrc[u] = BT + (size_t)(n0 + (u - 1) * 128 + (t >> 2)) * K + sslot * 8;

  int abyte[4], bbyte[FN];
#pragma unroll
  for (int f = 0; f < 4; ++f) {
    const int r = wm * 64 + f * 16 + l16;
    abyte[f] = r * 64 + ((lq ^ ((r >> 1) & 3)) << 4);
  }
#pragma unroll
  for (int j = 0; j < FN; ++j) {
    const int r = wn * (BN / 4) + j * 16 + l16;
    bbyte[j] = CA + r * 64 + ((lq ^ ((r >> 1) & 3)) << 4);
  }

  auto stage = [&](int kt) {
    char* d = smem + (kt & 3) * BUF + t * 16;
#pragma unroll
    for (int u = 0; u < LTOT; ++u) async16(gsrc[u] + (size_t)kt * 32, d + u * 8192);
  };
  auto ldfrag = [&](int kt, bf16x8(&a)[4], bf16x8(&b)[FN]) {
    const char* buf = smem + (kt & 3) * BUF;
#pragma unroll
    for (int f = 0; f < 4; ++f) a[f] = *(const bf16x8*)(buf + abyte[f]);
#pragma unroll
    for (int j = 0; j < FN; ++j) b[j] = *(const bf16x8*)(buf + bbyte[j]);
  };

  f32x4 acc[4][FN] = {};
  const int NT = K >> 5;  // 128 (even)

  bf16x8 a0[4], a1[4], b0[FN], b1[FN];

  // prologue: stage tiles 0..2; certify tile 0; frags(0) -> set 0
  stage(0);
  stage(1);
  stage(2);
  if constexpr (LTOT == 4) { VMCNT(8); } else { VMCNT(6); }
  barrier_raw();
  ldfrag(0, a0, b0);

  auto tilestep = [&](int kt, bf16x8(&aC)[4], bf16x8(&bC)[FN], bf16x8(&aN)[4],
                      bf16x8(&bN)[FN]) {
    if (kt + 3 < NT) {
      stage(kt + 3);
      if constexpr (LTOT == 4) { VMCNT(8); } else { VMCNT(6); }
    } else if (kt + 2 < NT) {
      if constexpr (LTOT == 4) { VMCNT(4); } else { VMCNT(3); }
    } else if (kt + 1 < NT) {
      VMCNT(0);
    }
    LGKM0;  // ldfrag(kt) complete -> barrier makes next tile's WAR overwrite safe
    barrier_raw();
    if (kt + 1 < NT) ldfrag(kt + 1, aN, bN);  // overlaps MFMA(kt) on the LDS pipe
    __builtin_amdgcn_s_setprio(1);
#pragma unroll
    for (int f = 0; f < 4; ++f)
#pragma unroll
      for (int j = 0; j < FN; ++j) acc[f][j] = MFMA(aC[f], bC[j], acc[f][j]);
    __builtin_amdgcn_s_setprio(0);
  };

  for (int kt = 0; kt < NT; kt += 2) {
    tilestep(kt, a0, b0, a1, b1);
    tilestep(kt + 1, a1, b1, a0, b0);
  }

#pragma unroll
  for (int f = 0; f < 4; ++f)
#pragma unroll
    for (int j = 0; j < FN; ++j)
#pragma unroll
      for (int r = 0; r < 4; ++r) {
        const int row = m0 + wm * 64 + f * 16 + lq * 4 + r;
        const int col = n0 + wn * (BN / 4) + j * 16 + l16;
        if (OUT_BF16)
          ((bf16*)Cout)[(size_t)row * N + col] = (bf16)acc[f][j][r];
        else
          ((float*)Cout)[(size_t)row * N + col] = acc[f][j][r];
      }
}

// ---------------- RoPE + reshape ----------------
__global__ __launch_bounds__(256) void rope_reshape(const bf16* __restrict__ qkv,
                                                    const float* __restrict__ cosp,
                                                    const float* __restrict__ sinp,
                                                    bf16* __restrict__ Qo,
                                                    bf16* __restrict__ Ko,
                                                    bf16* __restrict__ VTo) {
  const int row = blockIdx.x;          // b*SEQ + s
  const int b = row >> 10, s = row & 1023;
  const bf16* src = qkv + (size_t)row * QKV_N;
  for (int p = threadIdx.x; p < QKV_N / 2; p += 256) {
    const int col = p * 2;
    bf16x2 x = *(const bf16x2*)&src[col];
    const float x1 = (float)x.x, x2 = (float)x.y;
    if (col < 4096) {
      const int h = col >> 7, d = col & 127, i = (col & 127) >> 1;
      const float c = cosp[s * 64 + i], sn = sinp[s * 64 + i];
      bf16x2 o = {(bf16)((x1 * c - x2 * sn) * SCALE), (bf16)((x1 * sn + x2 * c) * SCALE)};
      *(bf16x2*)&Qo[((size_t)(b * NH + h) * SEQ + s) * DH + d] = o;
    } else if (col < 5120) {
      const int idx = col - 4096;
      const int kvh = idx >> 7, d = idx & 127, i = (idx & 127) >> 1;
      const float c = cosp[s * 64 + i], sn = sinp[s * 64 + i];
      bf16x2 o = {(bf16)(x1 * c - x2 * sn), (bf16)(x1 * sn + x2 * c)};
      *(bf16x2*)&Ko[((size_t)(b * NKV + kvh) * SEQ + s) * DH + d] = o;
    } else {
      const int idx = col - 5120;
      const int kvh = idx >> 7, d = idx & 127;
      bf16* vbase = VTo + ((size_t)(b * NKV + kvh) * DH + d) * SEQ + s;
      vbase[0] = x.x;
      vbase[SEQ] = x.y;
    }
  }
}

// ======== causal GQA flash attention v2: 8-wave blocks, LDS-staged K/V (R8, kept) ====
__global__ __launch_bounds__(512, 2) void flash_attn(const bf16* __restrict__ Q,
                                                     const bf16* __restrict__ K,
                                                     const bf16* __restrict__ VT,
                                                     bf16* __restrict__ O) {
  extern __shared__ char smem[];
  const int t = threadIdx.x, lane = t & 63, w = t >> 6;
  const int l16 = lane & 15, lq = lane >> 4;
  const int p = blockIdx.x;
  const int b = p >> 7, h = (p >> 2) & 31, Tb = p & 3;
  const int kvh = h >> 2;

  const bf16* Qb = Q + (size_t)(b * NH + h) * SEQ * DH;
  const bf16* Kb = K + (size_t)(b * NKV + kvh) * SEQ * DH;
  const bf16* Vb = VT + (size_t)(b * NKV + kvh) * DH * SEQ;

  const int qrA = Tb * 128 + w * 16;
  const int qrB = (7 - Tb) * 128 + w * 16;
  const int nAw = (qrA >> 6) + 1;
  const int nBw = (qrB >> 6) + 1;
  const int NT = 16 - 2 * Tb;

  bf16* plw = (bf16*)(smem + 98304) + w * (2 * 16 * 72);

  const bf16* kSrc = Kb + (size_t)(t >> 4) * DH + 8 * ((t & 15) ^ ((t >> 4) & 7));
  const bf16* vSrc = Vb + (size_t)(t >> 3) * SEQ + 8 * ((t & 7) ^ ((t >> 3) & 7));

  auto stage = [&](int kv) {
    char* bufb = smem + (kv % 3) * 32768;
    async16(kSrc + (size_t)(kv * 64) * DH, bufb + t * 16);
    async16(kSrc + (size_t)(kv * 64 + 32) * DH, bufb + 8192 + t * 16);
    async16(vSrc + kv * 64, bufb + 16384 + t * 16);
    async16(vSrc + (size_t)64 * SEQ + kv * 64, bufb + 24576 + t * 16);
  };

  int KX[4], VX[2];
#pragma unroll
  for (int kk = 0; kk < 4; ++kk) KX[kk] = ((kk * 4 + lq) ^ (l16 & 7)) << 4;
#pragma unroll
  for (int c = 0; c < 2; ++c) VX[c] = ((c * 4 + lq) ^ (l16 & 7)) << 4;

  bf16x8 qfA[4], qfB[4];
#pragma unroll
  for (int kk = 0; kk < 4; ++kk) {
    qfA[kk] = *(const bf16x8*)&Qb[(size_t)(qrA + l16) * DH + kk * 32 + lq * 8];
    qfB[kk] = *(const bf16x8*)&Qb[(size_t)(qrB + l16) * DH + kk * 32 + lq * 8];
  }

  f32x4 accA[8] = {}, accB[8] = {};
  float mA[4], lA[4], mB[4], lB[4];
#pragma unroll
  for (int r = 0; r < 4; ++r) {
    mA[r] = mB[r] = -INFINITY;
    lA[r] = lB[r] = 0.f;
  }

  auto finish = [&](f32x4(&s)[4], float(&m)[4], float(&l)[4], f32x4(&acc)[8], int slot,
                    bool mask, int kv, int qr) {
    if (mask) {
#pragma unroll
      for (int nt = 0; nt < 4; ++nt)
#pragma unroll
        for (int r = 0; r < 4; ++r)
          if (kv * 64 + nt * 16 + l16 > qr + lq * 4 + r) s[nt][r] = -INFINITY;
    }
#pragma unroll
    for (int r = 0; r < 4; ++r) {
      float mx = fmaxf(fmaxf(s[0][r], s[1][r]), fmaxf(s[2][r], s[3][r]));
#pragma unroll
      for (int off = 1; off < 16; off <<= 1) mx = fmaxf(mx, __shfl_xor(mx, off));
      const float mn = fmaxf(m[r], mx);
      const float corr = __expf(m[r] - mn);
      m[r] = mn;
      float ps = 0.f;
#pragma unroll
      for (int nt = 0; nt < 4; ++nt) {
        const float pv = __expf(s[nt][r] - mn);
        s[nt][r] = pv;
        ps += pv;
      }
#pragma unroll
      for (int off = 1; off < 16; off <<= 1) ps += __shfl_xor(ps, off);
      l[r] = l[r] * corr + ps;
#pragma unroll
      for (int j = 0; j < 8; ++j) acc[j][r] *= corr;
    }
#pragma unroll
    for (int nt = 0; nt < 4; ++nt)
#pragma unroll
      for (int r = 0; r < 4; ++r)
        plw[slot * 1152 + (lq * 4 + r) * 72 + nt * 16 + l16] = (bf16)s[nt][r];
  };

  stage(0);
  stage(1);
  VMCNT(4);
  barrier_raw();

  for (int kv = 0; kv < NT; ++kv) {
    const char* kbuf = smem + (kv % 3) * 32768;
    const char* vbuf = kbuf + 16384;
    if (kv + 2 < NT) stage(kv + 2);

    if (kv < nAw) {
      f32x4 sA[4] = {}, sB[4] = {};
      __builtin_amdgcn_s_setprio(1);
#pragma unroll
      for (int nt = 0; nt < 4; ++nt) {
        const char* kr = kbuf + (nt * 16 + l16) * 256;
        bf16x8 k0 = *(const bf16x8*)(kr + KX[0]);
        bf16x8 k1 = *(const bf16x8*)(kr + KX[1]);
        bf16x8 k2 = *(const bf16x8*)(kr + KX[2]);
        bf16x8 k3 = *(const bf16x8*)(kr + KX[3]);
        sA[nt] = MFMA(qfA[0], k0, sA[nt]);
        sB[nt] = MFMA(qfB[0], k0, sB[nt]);
        sA[nt] = MFMA(qfA[1], k1, sA[nt]);
        sB[nt] = MFMA(qfB[1], k1, sB[nt]);
        sA[nt] = MFMA(qfA[2], k2, sA[nt]);
        sB[nt] = MFMA(qfB[2], k2, sB[nt]);
        sA[nt] = MFMA(qfA[3], k3, sA[nt]);
        sB[nt] = MFMA(qfB[3], k3, sB[nt]);
      }
      __builtin_amdgcn_s_setprio(0);
      finish(sA, mA, lA, accA, 0, kv == nAw - 1, kv, qrA);
      finish(sB, mB, lB, accB, 1, kv == nBw - 1, kv, qrB);
      bf16x8 pA0 = *(const bf16x8*)&plw[l16 * 72 + lq * 8];
      bf16x8 pA1 = *(const bf16x8*)&plw[l16 * 72 + 32 + lq * 8];
      bf16x8 pB0 = *(const bf16x8*)&plw[1152 + l16 * 72 + lq * 8];
      bf16x8 pB1 = *(const bf16x8*)&plw[1152 + l16 * 72 + 32 + lq * 8];
      __builtin_amdgcn_s_setprio(1);
#pragma unroll
      for (int j = 0; j < 8; ++j) {
        const char* vr = vbuf + (j * 16 + l16) * 128;
        bf16x8 v0 = *(const bf16x8*)(vr + VX[0]);
        bf16x8 v1 = *(const bf16x8*)(vr + VX[1]);
        accA[j] = MFMA(pA0, v0, accA[j]);
        accB[j] = MFMA(pB0, v0, accB[j]);
        accA[j] = MFMA(pA1, v1, accA[j]);
        accB[j] = MFMA(pB1, v1, accB[j]);
      }
      __builtin_amdgcn_s_setprio(0);
    } else if (kv < nBw) {
      f32x4 sB[4] = {};
      __builtin_amdgcn_s_setprio(1);
#pragma unroll
      for (int nt = 0; nt < 4; ++nt) {
        const char* kr = kbuf + (nt * 16 + l16) * 256;
        bf16x8 k0 = *(const bf16x8*)(kr + KX[0]);
        bf16x8 k1 = *(const bf16x8*)(kr + KX[1]);
        bf16x8 k2 = *(const bf16x8*)(kr + KX[2]);
        bf16x8 k3 = *(const bf16x8*)(kr + KX[3]);
        sB[nt] = MFMA(qfB[0], k0, sB[nt]);
        sB[nt] = MFMA(qfB[1], k1, sB[nt]);
        sB[nt] = MFMA(qfB[2], k2, sB[nt]);
        sB[nt] = MFMA(qfB[3], k3, sB[nt]);
      }
      __builtin_amdgcn_s_setprio(0);
      finish(sB, mB, lB, accB, 1, kv == nBw - 1, kv, qrB);
      bf16x8 pB0 = *(const bf16x8*)&plw[1152 + l16 * 72 + lq * 8];
      bf16x8 pB1 = *(const bf16x8*)&plw[1152 + l16 * 72 + 32 + lq * 8];
      __builtin_amdgcn_s_setprio(1);
#pragma unroll
      for (int j = 0; j < 8; ++j) {
        const char* vr = vbuf + (j * 16 + l16) * 128;
        bf16x8 v0 = *(const bf16x8*)(vr + VX[0]);
        bf16x8 v1 = *(const bf16x8*)(vr + VX[1]);
        accB[j] = MFMA(pB0, v0, accB[j]);
        accB[j] = MFMA(pB1, v1, accB[j]);
      }
      __builtin_amdgcn_s_setprio(0);
    }

    if (kv + 2 < NT) { VMCNT(4); } else { VMCNT(0); }
    barrier_raw();
  }

  auto wout = [&](f32x4(&acc)[8], float(&l)[4], int qr) {
#pragma unroll
    for (int r = 0; r < 4; ++r) {
      const float inv = 1.f / l[r];
      const size_t orow = ((size_t)b * SEQ + qr + lq * 4 + r) * HIDN + h * DH;
#pragma unroll
      for (int j = 0; j < 8; ++j) O[orow + j * 16 + l16] = (bf16)(acc[j][r] * inv);
    }
  };
  wout(accA, lA, qrA);
  wout(accB, lB, qrB);
}

extern "C" void kernel_launch(void* const* d_in, const int* in_sizes, int n_in,
                              void* d_out, int out_size, void* d_ws, size_t ws_size,
                              hipStream_t stream) {
  const float* hidden = (const float*)d_in[0];
  const float* cosp = (const float*)d_in[1];
  const float* sinp = (const float*)d_in[2];
  const float* wqkv = (const float*)d_in[3];
  const float* wo = (const float*)d_in[4];
  float* out = (float*)d_out;

  char* ws = (char*)d_ws;
  bf16* hiddenB = (bf16*)(ws);                 // 16,777,216   [2048][4096]
  bf16* wqkvT  = (bf16*)(ws + 16777216);       // 50,331,648   [6144][4096]
  bf16* woT    = (bf16*)(ws + 67108864);       // 33,554,432   [4096][4096]
  bf16* qkvB   = (bf16*)(ws + 100663296);      // 25,165,824   [2048][6144]
  bf16* Qb     = (bf16*)(ws + 125829120);      // 16,777,216   [2][32][1024][128]
  bf16* Kb     = (bf16*)(ws + 142606336);      //  4,194,304   [2][8][1024][128]
  bf16* VTb    = (bf16*)(ws + 146800640);      //  4,194,304   [2][8][128][1024]
  bf16* attnB  = hiddenB;                      // alias: hiddenB dead after gemm1

  cvt_f32_bf16<<<8192, 256, 0, stream>>>(hidden, hiddenB, 2097152);
  transpose_cvt<<<dim3(192, 128), 256, 0, stream>>>(wqkv, wqkvT, 4096, 6144);
  transpose_cvt<<<dim3(128, 128), 256, 0, stream>>>(wo, woT, 4096, 4096);
  gemm_dp2<384, 1><<<dim3(256), 512, 131072, stream>>>(hiddenB, wqkvT, qkvB, 6144, 4096);
  rope_reshape<<<2048, 256, 0, stream>>>(qkvB, cosp, sinp, Qb, Kb, VTb);
  flash_attn<<<dim3(256), 512, 135168, stream>>>(Qb, Kb, VTb, attnB);
  gemm_dp2<256, 0><<<dim3(256), 512, 98304, stream>>>(attnB, woT, out, 4096, 4096);
}